// Round 6
// baseline (289.787 us; speedup 1.0000x reference)
//
#include <hip/hip_runtime.h>

#define N_ROWS 1024
#define M_COLS 16384
#define DIM 512

constexpr float GAMMA_ = 0.1f;
constexpr float INV_GAMMA = 10.0f;
constexpr float EPS_ = 0.005f;
constexpr float TINY_ = 1e-30f;
constexpr float RVAL = 1.0f / 1024.0f;
constexpr float CVAL = 1.0f / 16384.0f;

typedef __attribute__((ext_vector_type(8))) short bf16x8;
typedef __attribute__((ext_vector_type(4))) float f32x4;

__device__ __forceinline__ float waveRedSum(float v) {
#pragma unroll
    for (int o = 32; o > 0; o >>= 1) v += __shfl_down(v, o);
    return v;
}

// ---- order-preserving float<->uint key (for atomicMin row-min) ----
__device__ __forceinline__ unsigned fkey(float x) {
    unsigned u = __float_as_uint(x);
    return (u & 0x80000000u) ? ~u : (u | 0x80000000u);
}
__device__ __forceinline__ float fdec(unsigned k) {
    unsigned u = (k & 0x80000000u) ? (k & 0x7FFFFFFFu) : ~k;
    return __uint_as_float(u);
}

// ---- L2-bypassing (coherent-point) accesses: relaxed system-scope atomics ----
__device__ __forceinline__ unsigned sysloadu(const unsigned* p) {
    return __hip_atomic_load(p, __ATOMIC_RELAXED, __HIP_MEMORY_SCOPE_SYSTEM);
}
__device__ __forceinline__ void sysstoreu(unsigned* p, unsigned v) {
    __hip_atomic_store(p, v, __ATOMIC_RELAXED, __HIP_MEMORY_SCOPE_SYSTEM);
}
__device__ __forceinline__ float sysloadf(const float* p) {
    return __hip_atomic_load(p, __ATOMIC_RELAXED, __HIP_MEMORY_SCOPE_SYSTEM);
}
__device__ __forceinline__ void sysstoref(float* p, float v) {
    __hip_atomic_store(p, v, __ATOMIC_RELAXED, __HIP_MEMORY_SCOPE_SYSTEM);
}

// ---- fence-free ALL-TO-ALL barrier: publish arrival, sweep all 256 flags ----
// Entry __syncthreads drains vmcnt -> this block's sc-stores are acked at the
// coherent point before the flag store issues; seeing arr[j]>=e therefore
// implies block j's data is visible to our sc-loads. Single-RTT critical path.
__device__ __forceinline__ void gbarx(unsigned* __restrict__ arr, int b, int tid, unsigned e) {
    __syncthreads();
    if (tid == 0) sysstoreu(&arr[b], e);
    if (tid < 256) {
        while (sysloadu(&arr[tid]) < e) __builtin_amdgcn_s_sleep(1);
    }
    __syncthreads();
}

// ---- sq norms: one block (128 thr) per row ----
__global__ void row_sqnorm(const float* __restrict__ X, float* __restrict__ out) {
    int row = blockIdx.x;
    const float* xr = X + (size_t)row * DIM;
    int tid = threadIdx.x;
    float acc = 0.f;
    for (int k = tid; k < DIM; k += 128) { float v = xr[k]; acc = fmaf(v, v, acc); }
    acc = waveRedSum(acc);
    __shared__ float red[2];
    if ((tid & 63) == 0) red[tid >> 6] = acc;
    __syncthreads();
    if (tid == 0) out[row] = red[0] + red[1];
}

// ---- bf16 split helpers ----
__device__ __forceinline__ unsigned bf16b(float f) {
    unsigned u = __float_as_uint(f);
    return (u + 0x7FFFu + ((u >> 16) & 1u)) >> 16;
}

// ---- M = sx + sy - 2*X@Y^T via split-bf16 MFMA + fused row-min atomics ----
__global__ __launch_bounds__(256, 2) void gemm_dist_mfma(const float* __restrict__ X, const float* __restrict__ Y,
                                                         const float* __restrict__ sx, const float* __restrict__ sy,
                                                         float* __restrict__ Mout, unsigned* __restrict__ MminKey) {
    __shared__ __align__(16) char lds[65536];
    char* Ahi = lds;
    char* Alo = lds + 16384;
    char* Bhi = lds + 32768;
    char* Blo = lds + 49152;
    const int tid = threadIdx.x;
    const int lane = tid & 63;
    const int w = tid >> 6;
    const int wm = w >> 1, wn = w & 1;
    const int bid = blockIdx.x;
    const int logical = (bid & 7) * 128 + (bid >> 3);
    const int ct = logical >> 3, rt = logical & 7;
    const int row0 = rt << 7, col0 = ct << 7;

    const int srow = tid >> 2;
    const int squar = tid & 3;

    f32x4 acc[4][4] = {};

    for (int k0 = 0; k0 < DIM; k0 += 64) {
        __syncthreads();
#pragma unroll
        for (int rr = 0; rr < 2; ++rr) {
            const int r = rr * 64 + srow;
            const int swz = (r & 7) << 4;
#pragma unroll
            for (int q = 0; q < 4; ++q) {
                const int kk = squar * 16 + q * 4;
                const int off = (r * 128 + kk * 2) ^ swz;
                {
                    float4 va = *(const float4*)(X + (size_t)(row0 + r) * DIM + k0 + kk);
                    unsigned h0 = bf16b(va.x), h1 = bf16b(va.y), h2 = bf16b(va.z), h3 = bf16b(va.w);
                    float l0f = va.x - __uint_as_float(h0 << 16);
                    float l1f = va.y - __uint_as_float(h1 << 16);
                    float l2f = va.z - __uint_as_float(h2 << 16);
                    float l3f = va.w - __uint_as_float(h3 << 16);
                    *(uint2*)(Ahi + off) = make_uint2(h0 | (h1 << 16), h2 | (h3 << 16));
                    *(uint2*)(Alo + off) = make_uint2(bf16b(l0f) | (bf16b(l1f) << 16),
                                                      bf16b(l2f) | (bf16b(l3f) << 16));
                }
                {
                    float4 vb = *(const float4*)(Y + (size_t)(col0 + r) * DIM + k0 + kk);
                    unsigned h0 = bf16b(vb.x), h1 = bf16b(vb.y), h2 = bf16b(vb.z), h3 = bf16b(vb.w);
                    float l0f = vb.x - __uint_as_float(h0 << 16);
                    float l1f = vb.y - __uint_as_float(h1 << 16);
                    float l2f = vb.z - __uint_as_float(h2 << 16);
                    float l3f = vb.w - __uint_as_float(h3 << 16);
                    *(uint2*)(Bhi + off) = make_uint2(h0 | (h1 << 16), h2 | (h3 << 16));
                    *(uint2*)(Blo + off) = make_uint2(bf16b(l0f) | (bf16b(l1f) << 16),
                                                      bf16b(l2f) | (bf16b(l3f) << 16));
                }
            }
        }
        __syncthreads();
#pragma unroll
        for (int ks = 0; ks < 2; ++ks) {
            const int kb = (ks * 32 + (lane >> 4) * 8) * 2;
            bf16x8 ah[4], al[4], bh[4], bl[4];
#pragma unroll
            for (int i = 0; i < 4; ++i) {
                const int r = wm * 64 + i * 16 + (lane & 15);
                const int offa = (r * 128 + kb) ^ ((r & 7) << 4);
                ah[i] = *(const bf16x8*)(Ahi + offa);
                al[i] = *(const bf16x8*)(Alo + offa);
                const int c = wn * 64 + i * 16 + (lane & 15);
                const int offb = (c * 128 + kb) ^ ((c & 7) << 4);
                bh[i] = *(const bf16x8*)(Bhi + offb);
                bl[i] = *(const bf16x8*)(Blo + offb);
            }
#pragma unroll
            for (int i = 0; i < 4; ++i)
#pragma unroll
                for (int j = 0; j < 4; ++j) {
                    acc[i][j] = __builtin_amdgcn_mfma_f32_16x16x32_bf16(ah[i], bh[j], acc[i][j], 0, 0, 0);
                    acc[i][j] = __builtin_amdgcn_mfma_f32_16x16x32_bf16(ah[i], bl[j], acc[i][j], 0, 0, 0);
                    acc[i][j] = __builtin_amdgcn_mfma_f32_16x16x32_bf16(al[i], bh[j], acc[i][j], 0, 0, 0);
                }
        }
    }
    // ---- epilogue: M = sx + sy - 2*acc; fused per-row min -> atomicMin keys ----
    const int lrow = lane >> 4;
    const int lcol = lane & 15;
#pragma unroll
    for (int i = 0; i < 4; ++i) {
        const int gr0 = row0 + wm * 64 + i * 16 + lrow * 4;
        const float sx0 = sx[gr0], sx1 = sx[gr0 + 1], sx2 = sx[gr0 + 2], sx3 = sx[gr0 + 3];
        float rmn0 = 1e30f, rmn1 = 1e30f, rmn2 = 1e30f, rmn3 = 1e30f;
#pragma unroll
        for (int j = 0; j < 4; ++j) {
            const int gc = col0 + wn * 64 + j * 16 + lcol;
            const float syv = sy[gc];
            float* op = Mout + (size_t)gr0 * M_COLS + gc;
            float m0 = sx0 + syv - 2.0f * acc[i][j][0];
            float m1 = sx1 + syv - 2.0f * acc[i][j][1];
            float m2 = sx2 + syv - 2.0f * acc[i][j][2];
            float m3 = sx3 + syv - 2.0f * acc[i][j][3];
            op[0]                  = m0;
            op[(size_t)1 * M_COLS] = m1;
            op[(size_t)2 * M_COLS] = m2;
            op[(size_t)3 * M_COLS] = m3;
            rmn0 = fminf(rmn0, m0); rmn1 = fminf(rmn1, m1);
            rmn2 = fminf(rmn2, m2); rmn3 = fminf(rmn3, m3);
        }
#pragma unroll
        for (int o = 1; o < 16; o <<= 1) {
            rmn0 = fminf(rmn0, __shfl_xor(rmn0, o));
            rmn1 = fminf(rmn1, __shfl_xor(rmn1, o));
            rmn2 = fminf(rmn2, __shfl_xor(rmn2, o));
            rmn3 = fminf(rmn3, __shfl_xor(rmn3, o));
        }
        if (lcol == 0) {
            atomicMin(&MminKey[gr0 + 0], fkey(rmn0));
            atomicMin(&MminKey[gr0 + 1], fkey(rmn1));
            atomicMin(&MminKey[gr0 + 2], fkey(rmn2));
            atomicMin(&MminKey[gr0 + 3], fkey(rmn3));
        }
    }
}

// ---- per-launch state init (graph replays do NOT re-poison ws/out) ----
__global__ void init_state(float* __restrict__ ubuf, unsigned* __restrict__ bar,
                           unsigned* __restrict__ MminKey, float* __restrict__ out) {
    int idx = blockIdx.x * blockDim.x + threadIdx.x;
    if (idx < 512) bar[idx] = 0u;
    if (idx < 1024) { ubuf[idx] = 1.0f; ubuf[1024 + idx] = 1.0f; MminKey[idx] = 0xFFFFFFFFu; }
    if (idx == 0) out[0] = 0.0f;
}

// ---- register-resident Sinkhorn, all-to-all fence-free barriers ----
__global__ __launch_bounds__(1024, 4) void sinkhorn_reg(const unsigned* __restrict__ MminKey,
                                                        float* __restrict__ ubuf,
                                                        float* __restrict__ out,
                                                        unsigned* __restrict__ bar) {
    const int tid = threadIdx.x;
    const int b = blockIdx.x;
    const int rg = tid >> 2;
    const int ch = tid & 3;
    const int r0 = rg << 2;
    const int c0 = b << 6;
    float* Pbuf = out + 1;
    float* spart = out + 4;               // [256 rg][256 writer][4 k] floats (1 MB)
    float* errpart = out + 4 + 262144;    // [256]
    unsigned* arr = bar;                  // [256]

    __shared__ float v_lds[2][64];
    __shared__ float u_lds[1024];
    __shared__ float t_acc[16][68];
    __shared__ float red[16];
    __shared__ float sh_err;

    if (tid < 64) { v_lds[0][tid] = 1.0f; v_lds[1][tid] = 1.0f; }

    float K[64];
#pragma unroll
    for (int k = 0; k < 4; ++k) {
        const float* mrow = Pbuf + (size_t)(r0 + k) * M_COLS + c0 + ch;
        float mm = fdec(MminKey[r0 + k]);
#pragma unroll
        for (int c = 0; c < 16; ++c) {
            K[k * 16 + c] = __expf(-GAMMA_ * (mrow[4 * c] - mm));
        }
    }
    gbarx(arr, b, tid, 1u);   // M fully consumed; scratch region writable

    int cur = 0, vsel = 0, brk = 0;
    unsigned ep = 2u;
    int it = 0;
    for (;; ++it, ep += 2u) {
        {
            float vv[16];
#pragma unroll
            for (int c = 0; c < 16; ++c) vv[c] = v_lds[cur][ch + 4 * c];
            float rs[4];
#pragma unroll
            for (int k = 0; k < 4; ++k) {
                float p = 0.f;
#pragma unroll
                for (int c = 0; c < 16; ++c) p = fmaf(K[k * 16 + c], vv[c], p);
                rs[k] = p;
            }
#pragma unroll
            for (int k = 0; k < 4; ++k) {
                rs[k] += __shfl_xor(rs[k], 1);
                rs[k] += __shfl_xor(rs[k], 2);
            }
            sysstoref(&spart[(size_t)(rg * 256 + b) * 4 + ch], rs[ch]);
        }
        gbarx(arr, b, tid, ep);   // barrier A: spart + prev errpart visible
        float* uOld = ubuf + (((it & 1) ^ 1) << 10);
        float* uNew = ubuf + ((it & 1) << 10);
        {
            const int w = tid >> 6, l = tid & 63;
            if (w == 0) {
                float e = 0.f;
                if (it > 0)
                    e = sysloadf(&errpart[l]) + sysloadf(&errpart[l + 64]) +
                        sysloadf(&errpart[l + 128]) + sysloadf(&errpart[l + 192]);
                e = waveRedSum(e);
                if (l == 0) sh_err = (it > 0) ? e : 1e30f;
            } else if (w <= 4) {
                const int k = w - 1;
                const float* sp = spart + ((size_t)b << 10) + k;
                float s = sysloadf(&sp[4 * l]) + sysloadf(&sp[4 * (l + 64)]) +
                          sysloadf(&sp[4 * (l + 128)]) + sysloadf(&sp[4 * (l + 192)]);
                s = waveRedSum(s);
                if (l == 0) {
                    int r = (b << 2) + k;
                    float uo = sysloadf(&uOld[r]);
                    sysstoref(&uNew[r], uo * RVAL / fmaxf(uo * s, TINY_));
                }
            }
        }
        __syncthreads();
        float err = sh_err;
        brk = (err <= EPS_) ? 1 : ((it == 1000) ? 2 : 0);
        gbarx(arr, b, tid, ep + 1u);  // barrier B: u visible / epilogue-safety
        if (brk) { vsel = (brk == 1) ? (cur ^ 1) : cur; break; }
        if (tid < 256) {
#pragma unroll
            for (int k = 0; k < 4; ++k) u_lds[tid * 4 + k] = sysloadf(&uNew[tid * 4 + k]);
        }
        __syncthreads();
        {
            float uu[4] = {u_lds[r0], u_lds[r0 + 1], u_lds[r0 + 2], u_lds[r0 + 3]};
            float t16[16];
#pragma unroll
            for (int c = 0; c < 16; ++c) {
                float t = 0.f;
#pragma unroll
                for (int k = 0; k < 4; ++k) t = fmaf(K[k * 16 + c], uu[k], t);
                t16[c] = t;
            }
#pragma unroll
            for (int c = 0; c < 16; ++c) {
                t16[c] += __shfl_xor(t16[c], 4);
                t16[c] += __shfl_xor(t16[c], 8);
                t16[c] += __shfl_xor(t16[c], 16);
                t16[c] += __shfl_xor(t16[c], 32);
            }
            const int w = tid >> 6, l = tid & 63;
            if (l < 4) {
#pragma unroll
                for (int c = 0; c < 16; ++c) t_acc[w][l + 4 * c] = t16[c];
            }
        }
        __syncthreads();
        if (tid < 64) {
            float t = 0.f;
#pragma unroll
            for (int w2 = 0; w2 < 16; ++w2) t += t_acc[w2][tid];
            float vc = v_lds[cur][tid];
            float beta = vc * t;
            float e = fabsf(beta - CVAL);
            v_lds[cur ^ 1][tid] = vc * CVAL / fmaxf(beta, TINY_);
            e = waveRedSum(e);
            if (tid == 0) sysstoref(&errpart[b], e);
        }
        __syncthreads();
        cur ^= 1;
    }

    // ---- epilogue: P = u K v (regs); loss = sum P*(Mmin - ln(K)/gamma) ----
    const float* uEpi = ubuf + (((it & 1) ^ 1) << 10);
    float vv[16];
#pragma unroll
    for (int c = 0; c < 16; ++c) vv[c] = v_lds[vsel][ch + 4 * c];
    float uu[4];
#pragma unroll
    for (int k = 0; k < 4; ++k) uu[k] = sysloadf(&uEpi[r0 + k]);
    float mm[4];
#pragma unroll
    for (int k = 0; k < 4; ++k) mm[k] = fdec(MminKey[r0 + k]);
    float lsum = 0.f;
#pragma unroll
    for (int k = 0; k < 4; ++k) {
        float* prow = Pbuf + (size_t)(r0 + k) * M_COLS + c0 + ch;
#pragma unroll
        for (int c = 0; c < 16; ++c) {
            float kv = K[k * 16 + c];
            float p = 0.f;
            if (kv > 0.f) {
                p = uu[k] * kv * vv[c];
                float m = mm[k] - __logf(kv) * INV_GAMMA;
                lsum = fmaf(p, m, lsum);
            }
            prow[4 * c] = p;
        }
    }
    lsum = waveRedSum(lsum);
    if ((tid & 63) == 0) red[tid >> 6] = lsum;
    __syncthreads();
    if (tid == 0) {
        float s = 0.f;
#pragma unroll
        for (int i = 0; i < 16; ++i) s += red[i];
        atomicAdd(out, s);
    }
}

extern "C" void kernel_launch(void* const* d_in, const int* in_sizes, int n_in,
                              void* d_out, int out_size, void* d_ws, size_t ws_size,
                              hipStream_t stream) {
    const float* x = (const float*)d_in[0];
    const float* y = (const float*)d_in[1];
    float* out = (float*)d_out;
    float* P = out + 1;
    float* ws = (float*)d_ws;
    float* sx   = ws;                        // 1024
    float* sy   = ws + 1024;                 // 16384
    unsigned* MminKey = (unsigned*)(ws + 17408); // 1024 uints
    float* ubuf = ws + 18432;                // 2 x 1024
    unsigned* bar = (unsigned*)(ws + 20480); // 512 uints

    row_sqnorm<<<N_ROWS, 128, 0, stream>>>(x, sx);
    row_sqnorm<<<M_COLS, 128, 0, stream>>>(y, sy);
    init_state<<<4, 256, 0, stream>>>(ubuf, bar, MminKey, out);
    gemm_dist_mfma<<<1024, 256, 0, stream>>>(x, y, sx, sy, P, MminKey);
    {
        const unsigned* Mk = MminKey;
        void* args[] = {(void*)&Mk, (void*)&ubuf, (void*)&out, (void*)&bar};
        hipLaunchCooperativeKernel((const void*)sinkhorn_reg, dim3(256), dim3(1024), args, 0, stream);
    }
}

// Round 7
// 235.803 us; speedup vs baseline: 1.2289x; 1.2289x over previous
//
#include <hip/hip_runtime.h>

#define N_ROWS 1024
#define M_COLS 16384
#define DIM 512

constexpr float GAMMA_ = 0.1f;
constexpr float INV_GAMMA = 10.0f;
constexpr float EPS_ = 0.005f;
constexpr float TINY_ = 1e-30f;
constexpr float RVAL = 1.0f / 1024.0f;
constexpr float CVAL = 1.0f / 16384.0f;

typedef __attribute__((ext_vector_type(8))) short bf16x8;
typedef __attribute__((ext_vector_type(4))) float f32x4;

__device__ __forceinline__ float waveRedSum(float v) {
#pragma unroll
    for (int o = 32; o > 0; o >>= 1) v += __shfl_down(v, o);
    return v;
}
__device__ __forceinline__ float waveRedMin(float v) {
#pragma unroll
    for (int o = 32; o > 0; o >>= 1) v = fminf(v, __shfl_down(v, o));
    return v;
}

// ---- L2-bypassing (coherent-point) accesses: relaxed system-scope atomics ----
__device__ __forceinline__ unsigned sysloadu(const unsigned* p) {
    return __hip_atomic_load(p, __ATOMIC_RELAXED, __HIP_MEMORY_SCOPE_SYSTEM);
}
__device__ __forceinline__ void sysstoreu(unsigned* p, unsigned v) {
    __hip_atomic_store(p, v, __ATOMIC_RELAXED, __HIP_MEMORY_SCOPE_SYSTEM);
}
__device__ __forceinline__ float sysloadf(const float* p) {
    return __hip_atomic_load(p, __ATOMIC_RELAXED, __HIP_MEMORY_SCOPE_SYSTEM);
}
__device__ __forceinline__ void sysstoref(float* p, float v) {
    __hip_atomic_store(p, v, __ATOMIC_RELAXED, __HIP_MEMORY_SCOPE_SYSTEM);
}

// ---- fence-free barrier, R5 topology (block0 sweeps, broadcasts): ~0.95us ----
__device__ __forceinline__ void gbarx(unsigned* __restrict__ arr, unsigned* __restrict__ bcast,
                                      int b, int tid, unsigned e) {
    __syncthreads();                       // drains vmcnt: all waves' sys-stores acked at L3
    if (tid == 0) sysstoreu(&arr[b], e);
    if (b == 0) {
        if (tid < 256) {
            while (sysloadu(&arr[tid]) < e) __builtin_amdgcn_s_sleep(1);
        }
        __syncthreads();
        if (tid == 0) sysstoreu(bcast, e);
    } else {
        if (tid == 0) {
            while (sysloadu(bcast) < e) __builtin_amdgcn_s_sleep(1);
        }
    }
    __syncthreads();
}

// ---- bf16 split helper (RNE) ----
__device__ __forceinline__ unsigned bf16b(float f) {
    unsigned u = __float_as_uint(f);
    return (u + 0x7FFFu + ((u >> 16) & 1u)) >> 16;
}

// ---- conv_x: f32 -> bf16 hi/lo (linear layout) + row sqnorm. 1024 blk x 64 thr ----
__global__ void conv_x(const float* __restrict__ X, unsigned short* __restrict__ xh,
                       unsigned short* __restrict__ xl, float* __restrict__ sx) {
    const int row = blockIdx.x, t = threadIdx.x;
    const float* xr = X + (size_t)row * DIM + t * 8;
    float4 a = *(const float4*)xr, c = *(const float4*)(xr + 4);
    float v[8] = {a.x, a.y, a.z, a.w, c.x, c.y, c.z, c.w};
    unsigned hs[8], ls[8];
    float sq = 0.f;
#pragma unroll
    for (int j = 0; j < 8; ++j) {
        unsigned h = bf16b(v[j]);
        hs[j] = h;
        ls[j] = bf16b(v[j] - __uint_as_float(h << 16));
        sq = fmaf(v[j], v[j], sq);
    }
    uint4 hv = make_uint4(hs[0] | (hs[1] << 16), hs[2] | (hs[3] << 16),
                          hs[4] | (hs[5] << 16), hs[6] | (hs[7] << 16));
    uint4 lv = make_uint4(ls[0] | (ls[1] << 16), ls[2] | (ls[3] << 16),
                          ls[4] | (ls[5] << 16), ls[6] | (ls[7] << 16));
    const size_t off = (size_t)row * 1024 + t * 16;   // bytes
    *(uint4*)((char*)xh + off) = hv;
    *(uint4*)((char*)xl + off) = lv;
    sq = waveRedSum(sq);
    if (t == 0) sx[row] = sq;
}

// ---- conv_y: same but output PRE-SWIZZLED (byte ^ ((row&7)<<4) within each 1KB row)
// so the fused kernel's LDS tile copy is linear and ds_read applies the same XOR ----
__global__ void conv_y(const float* __restrict__ Y, unsigned short* __restrict__ yh,
                       unsigned short* __restrict__ yl, float* __restrict__ sy) {
    const int row = blockIdx.x, t = threadIdx.x;
    const float* yr = Y + (size_t)row * DIM + t * 8;
    float4 a = *(const float4*)yr, c = *(const float4*)(yr + 4);
    float v[8] = {a.x, a.y, a.z, a.w, c.x, c.y, c.z, c.w};
    unsigned hs[8], ls[8];
    float sq = 0.f;
#pragma unroll
    for (int j = 0; j < 8; ++j) {
        unsigned h = bf16b(v[j]);
        hs[j] = h;
        ls[j] = bf16b(v[j] - __uint_as_float(h << 16));
        sq = fmaf(v[j], v[j], sq);
    }
    uint4 hv = make_uint4(hs[0] | (hs[1] << 16), hs[2] | (hs[3] << 16),
                          hs[4] | (hs[5] << 16), hs[6] | (hs[7] << 16));
    uint4 lv = make_uint4(ls[0] | (ls[1] << 16), ls[2] | (ls[3] << 16),
                          ls[4] | (ls[5] << 16), ls[6] | (ls[7] << 16));
    const size_t off = ((size_t)row * 1024 + t * 16) ^ ((size_t)((row & 7) << 4));
    *(uint4*)((char*)yh + off) = hv;
    *(uint4*)((char*)yl + off) = lv;
    sq = waveRedSum(sq);
    if (t == 0) sy[row] = sq;
}

// ---- per-launch state init (graph replays do NOT re-poison ws/out) ----
__global__ void init_state(float* __restrict__ ubuf, unsigned* __restrict__ bar,
                           float* __restrict__ out) {
    int idx = blockIdx.x * blockDim.x + threadIdx.x;
    if (idx < 512) bar[idx] = 0u;
    if (idx < 1024) { ubuf[idx] = 1.0f; ubuf[1024 + idx] = 1.0f; }
    if (idx == 0) out[0] = 0.0f;
}

// ---- FUSED: split-bf16 MFMA gemm (K tile in MFMA C-fragments) + row-min
// exchange + K=exp + register-resident Sinkhorn + P/loss epilogue.
// 256 blocks x 1024 thr (16 waves). Block b owns cols [64b,64b+64), wave w
// owns rows [64w,64w+64). Thread frag kf[i][j][reg]:
//   row = 64w + 16i + 4q + reg  (q = lane>>4), col(local) = 16j + l15.
__global__ __launch_bounds__(1024, 4) void sinkhorn_full(
        const unsigned short* __restrict__ xh, const unsigned short* __restrict__ xl,
        const unsigned short* __restrict__ yh, const unsigned short* __restrict__ yl,
        const float* __restrict__ sx, const float* __restrict__ sy,
        float* __restrict__ ubuf, float* __restrict__ Mming,
        float* __restrict__ out, unsigned* __restrict__ bar) {
    const int tid = threadIdx.x;
    const int b = blockIdx.x;
    const int lane = tid & 63;
    const int w = tid >> 6;
    const int l15 = lane & 15;
    const int q = lane >> 4;
    float* Pbuf = out + 1;
    float* spart = out + 4;            // [1024 rows][256 writers] f32 (also min-partials)
    float* errpart = out + 270000;     // [256]
    unsigned* arr = bar;
    unsigned* bcast = bar + 288;

    __shared__ __align__(16) char ldsY[131072];   // yh tile 64KB | yl tile 64KB (swizzled)
    __shared__ float sx_lds[1024];
    __shared__ float mmin_lds[1024];
    __shared__ float u_lds[1024];
    __shared__ float sy_lds[64];
    __shared__ float v_lds[2][64];
    __shared__ float t_acc[16][68];
    __shared__ float red[16];
    __shared__ float sh_err;

    // ---- stage y tile (swizzle-preserving linear 128KB copy) + small state ----
    {
        const char* ysrcH = (const char*)yh + (size_t)b * 65536;
        const char* ysrcL = (const char*)yl + (size_t)b * 65536;
#pragma unroll
        for (int p = 0; p < 4; ++p) {
            const int d = tid * 16 + p * 16384;
            *(uint4*)(ldsY + d) = *(const uint4*)(ysrcH + d);
            *(uint4*)(ldsY + 65536 + d) = *(const uint4*)(ysrcL + d);
        }
        sx_lds[tid] = sx[tid];
        if (tid < 64) {
            sy_lds[tid] = sy[(b << 6) + tid];
            v_lds[0][tid] = 1.0f;
            v_lds[1][tid] = 1.0f;
        }
    }
    __syncthreads();

    // ---- gemm phase: kf = x . y^T for this block's tile (3-pass split bf16) ----
    f32x4 kf[4][4] = {};
    {
        const int rowbase = (w << 6) + l15;
        const int kofs = q * 8;     // shorts within the 32-k step
#pragma unroll 1
        for (int ks = 0; ks < 16; ++ks) {
            bf16x8 ah[4], al[4], bh[4], bl[4];
#pragma unroll
            for (int i = 0; i < 4; ++i) {
                const size_t xo = (size_t)(rowbase + i * 16) * 512 + ks * 32 + kofs;
                ah[i] = *(const bf16x8*)(xh + xo);
                al[i] = *(const bf16x8*)(xl + xo);
                const int cl = i * 16 + l15;
                const int bo = (cl * 1024 + ks * 64 + q * 16) ^ ((cl & 7) << 4);
                bh[i] = *(const bf16x8*)(ldsY + bo);
                bl[i] = *(const bf16x8*)(ldsY + 65536 + bo);
            }
#pragma unroll
            for (int i = 0; i < 4; ++i)
#pragma unroll
                for (int j = 0; j < 4; ++j) {
                    kf[i][j] = __builtin_amdgcn_mfma_f32_16x16x32_bf16(ah[i], bh[j], kf[i][j], 0, 0, 0);
                    kf[i][j] = __builtin_amdgcn_mfma_f32_16x16x32_bf16(ah[i], bl[j], kf[i][j], 0, 0, 0);
                    kf[i][j] = __builtin_amdgcn_mfma_f32_16x16x32_bf16(al[i], bh[j], kf[i][j], 0, 0, 0);
                }
        }
    }
    // ---- kf := M = sx + sy - 2*dot; publish block-partial row-mins ----
#pragma unroll
    for (int i = 0; i < 4; ++i)
#pragma unroll
        for (int j = 0; j < 4; ++j) {
            const float syv = sy_lds[j * 16 + l15];
#pragma unroll
            for (int reg = 0; reg < 4; ++reg) {
                const int r = (w << 6) + i * 16 + (q << 2) + reg;
                kf[i][j][reg] = sx_lds[r] + syv - 2.0f * kf[i][j][reg];
            }
        }
    {
        float mn[4][4];
#pragma unroll
        for (int i = 0; i < 4; ++i)
#pragma unroll
            for (int reg = 0; reg < 4; ++reg) {
                float m = fminf(fminf(kf[i][0][reg], kf[i][1][reg]),
                                fminf(kf[i][2][reg], kf[i][3][reg]));
#pragma unroll
                for (int o = 1; o < 16; o <<= 1) m = fminf(m, __shfl_xor(m, o));
                mn[i][reg] = m;
            }
        if (l15 == 0) {
#pragma unroll
            for (int i = 0; i < 4; ++i)
#pragma unroll
                for (int reg = 0; reg < 4; ++reg) {
                    const int r = (w << 6) + i * 16 + (q << 2) + reg;
                    sysstoref(&spart[(size_t)r * 256 + b], mn[i][reg]);
                }
        }
    }
    gbarx(arr, bcast, b, tid, 1u);
    // owner block b reduces rows 4b..4b+3 (waves 1..4)
    if (w >= 1 && w <= 4) {
        const int r = (b << 2) + (w - 1);
        const float* sp = spart + (size_t)r * 256;
        float m = fminf(fminf(sysloadf(&sp[lane]), sysloadf(&sp[lane + 64])),
                        fminf(sysloadf(&sp[lane + 128]), sysloadf(&sp[lane + 192])));
        m = waveRedMin(m);
        if (lane == 0) sysstoref(&Mming[r], m);
    }
    gbarx(arr, bcast, b, tid, 2u);
    // broadcast Mmin, K = exp(-gamma*(M - Mmin))
    if (tid < 256) {
#pragma unroll
        for (int k2 = 0; k2 < 4; ++k2) mmin_lds[tid * 4 + k2] = sysloadf(&Mming[tid * 4 + k2]);
    }
    __syncthreads();
#pragma unroll
    for (int i = 0; i < 4; ++i)
#pragma unroll
        for (int j = 0; j < 4; ++j)
#pragma unroll
            for (int reg = 0; reg < 4; ++reg) {
                const int r = (w << 6) + i * 16 + (q << 2) + reg;
                kf[i][j][reg] = __expf(-GAMMA_ * (kf[i][j][reg] - mmin_lds[r]));
            }

    // ---- Sinkhorn loop (R5 semantics, fragment-layout reductions) ----
    int cur = 0, vsel = 0, brk = 0;
    unsigned ep = 3u;
    int it = 0;
    for (;; ++it, ep += 2u) {
        // pass 1: row-partial s for this block's 64 cols
        {
            float vv[4];
#pragma unroll
            for (int j = 0; j < 4; ++j) vv[j] = v_lds[cur][j * 16 + l15];
            float rs[4][4];
#pragma unroll
            for (int i = 0; i < 4; ++i)
#pragma unroll
                for (int reg = 0; reg < 4; ++reg) {
                    float p = kf[i][0][reg] * vv[0];
                    p = fmaf(kf[i][1][reg], vv[1], p);
                    p = fmaf(kf[i][2][reg], vv[2], p);
                    p = fmaf(kf[i][3][reg], vv[3], p);
#pragma unroll
                    for (int o = 1; o < 16; o <<= 1) p += __shfl_xor(p, o);
                    rs[i][reg] = p;
                }
            if (l15 == 0) {
#pragma unroll
                for (int i = 0; i < 4; ++i)
#pragma unroll
                    for (int reg = 0; reg < 4; ++reg) {
                        const int r = (w << 6) + i * 16 + (q << 2) + reg;
                        sysstoref(&spart[(size_t)r * 256 + b], rs[i][reg]);
                    }
            }
        }
        gbarx(arr, bcast, b, tid, ep);   // barrier A: spart + prev errpart visible
        float* uOld = ubuf + (((it & 1) ^ 1) << 10);
        float* uNew = ubuf + ((it & 1) << 10);
        {
            if (w == 0) {
                float e = 0.f;
                if (it > 0)
                    e = sysloadf(&errpart[lane]) + sysloadf(&errpart[lane + 64]) +
                        sysloadf(&errpart[lane + 128]) + sysloadf(&errpart[lane + 192]);
                e = waveRedSum(e);
                if (lane == 0) sh_err = (it > 0) ? e : 1e30f;
            } else if (w <= 4) {
                const int r = (b << 2) + (w - 1);
                const float* sp = spart + (size_t)r * 256;
                float s = sysloadf(&sp[lane]) + sysloadf(&sp[lane + 64]) +
                          sysloadf(&sp[lane + 128]) + sysloadf(&sp[lane + 192]);
                s = waveRedSum(s);
                if (lane == 0) {
                    float uo = sysloadf(&uOld[r]);
                    sysstoref(&uNew[r], uo * RVAL / fmaxf(uo * s, TINY_));  // speculative at break
                }
            }
        }
        __syncthreads();
        float err = sh_err;
        brk = (err <= EPS_) ? 1 : ((it == 1000) ? 2 : 0);
        gbarx(arr, bcast, b, tid, ep + 1u);  // barrier B: u visible / epilogue-safety
        if (brk) { vsel = (brk == 1) ? (cur ^ 1) : cur; break; }
        if (tid < 256) {
#pragma unroll
            for (int k2 = 0; k2 < 4; ++k2) u_lds[tid * 4 + k2] = sysloadf(&uNew[tid * 4 + k2]);
        }
        __syncthreads();
        // pass 2: t for own 64 cols; v update; err partial
        {
            float uu[4][4];
#pragma unroll
            for (int i = 0; i < 4; ++i)
#pragma unroll
                for (int reg = 0; reg < 4; ++reg)
                    uu[i][reg] = u_lds[(w << 6) + i * 16 + (q << 2) + reg];
            float tj[4];
#pragma unroll
            for (int j = 0; j < 4; ++j) {
                float t = 0.f;
#pragma unroll
                for (int i = 0; i < 4; ++i)
#pragma unroll
                    for (int reg = 0; reg < 4; ++reg)
                        t = fmaf(kf[i][j][reg], uu[i][reg], t);
                t += __shfl_xor(t, 16);
                t += __shfl_xor(t, 32);
                tj[j] = t;
            }
            if (q == 0) {
#pragma unroll
                for (int j = 0; j < 4; ++j) t_acc[w][j * 16 + l15] = tj[j];
            }
        }
        __syncthreads();
        if (tid < 64) {
            float t = 0.f;
#pragma unroll
            for (int w2 = 0; w2 < 16; ++w2) t += t_acc[w2][tid];
            float vc = v_lds[cur][tid];
            float beta = vc * t;
            float e = fabsf(beta - CVAL);
            v_lds[cur ^ 1][tid] = vc * CVAL / fmaxf(beta, TINY_);
            e = waveRedSum(e);
            if (tid == 0) sysstoref(&errpart[b], e);
        }
        __syncthreads();
        cur ^= 1;
    }

    // ---- epilogue: P = u K v (regs); loss = sum P*(Mmin - ln(K)/gamma) ----
    const float* uEpi = ubuf + (((it & 1) ^ 1) << 10);
    if (tid < 256) {
#pragma unroll
        for (int k2 = 0; k2 < 4; ++k2) u_lds[tid * 4 + k2] = sysloadf(&uEpi[tid * 4 + k2]);
    }
    __syncthreads();
    float vv[4];
#pragma unroll
    for (int j = 0; j < 4; ++j) vv[j] = v_lds[vsel][j * 16 + l15];
    float lsum = 0.f;
#pragma unroll
    for (int i = 0; i < 4; ++i)
#pragma unroll
        for (int reg = 0; reg < 4; ++reg) {
            const int r = (w << 6) + i * 16 + (q << 2) + reg;
            const float ur = u_lds[r];
            const float mmr = mmin_lds[r];
            float* prow = Pbuf + (size_t)r * M_COLS + (b << 6) + l15;
#pragma unroll
            for (int j = 0; j < 4; ++j) {
                float kv = kf[i][j][reg];
                float p = 0.f;
                if (kv > 0.f) {
                    p = ur * kv * vv[j];
                    lsum = fmaf(p, mmr - __logf(kv) * INV_GAMMA, lsum);
                }
                prow[j * 16] = p;
            }
        }
    lsum = waveRedSum(lsum);
    if (lane == 0) red[w] = lsum;
    __syncthreads();
    if (tid == 0) {
        float s = 0.f;
#pragma unroll
        for (int i2 = 0; i2 < 16; ++i2) s += red[i2];
        atomicAdd(out, s);
    }
}

extern "C" void kernel_launch(void* const* d_in, const int* in_sizes, int n_in,
                              void* d_out, int out_size, void* d_ws, size_t ws_size,
                              hipStream_t stream) {
    const float* x = (const float*)d_in[0];
    const float* y = (const float*)d_in[1];
    float* out = (float*)d_out;
    float* ws = (float*)d_ws;
    float* sx   = ws;                        // 1024
    float* sy   = ws + 1024;                 // 16384
    float* Mming = ws + 17408;               // 1024
    float* ubuf = ws + 18432;                // 2 x 1024
    unsigned* bar = (unsigned*)(ws + 20480); // 512 uints

    // scratch inside the dead P-region of d_out (all consumed before P write):
    unsigned short* xh = (unsigned short*)(out + 300000);   // 1024x512 bf16
    unsigned short* xl = (unsigned short*)(out + 600000);
    unsigned short* yh = (unsigned short*)(out + 900000);   // 16384x512 bf16 (pre-swizzled)
    unsigned short* yl = (unsigned short*)(out + 5200000);

    conv_x<<<N_ROWS, 64, 0, stream>>>(x, xh, xl, sx);
    conv_y<<<M_COLS, 64, 0, stream>>>(y, yh, yl, sy);
    init_state<<<4, 256, 0, stream>>>(ubuf, bar, out);
    {
        const unsigned short *xhc = xh, *xlc = xl, *yhc = yh, *ylc = yl;
        const float *sxc = sx, *syc = sy;
        void* args[] = {(void*)&xhc, (void*)&xlc, (void*)&yhc, (void*)&ylc,
                        (void*)&sxc, (void*)&syc, (void*)&ubuf, (void*)&Mming,
                        (void*)&out, (void*)&bar};
        hipLaunchCooperativeKernel((const void*)sinkhorn_full, dim3(256), dim3(1024), args, 0, stream);
    }
}